// Round 21
// baseline (917.097 us; speedup 1.0000x reference)
//
#include <hip/hip_runtime.h>
#include <math.h>

#define NPTS 8192
#define KNN 20
#define KSEL 8    // per-stream ripple depth; subset-20th stays an upper bound
#define CAPD3 256 // d3 survivor cap (exact-key path)
#define CAP64 512 // 64-D survivor cap (split-bf16 filter path)
#define LCAP 2048 // d3 per-block LDS survivor list
#define LCAPM 1024 // recover_mfma per-block LDS list (mean ~55, >>10 sigma)

typedef __attribute__((ext_vector_type(8))) short bf16x8;
typedef __attribute__((ext_vector_type(16))) float f32x16;

// monotonic u32 key: a<b (float, incl. inf) <=> fkey(a)<fkey(b)
__device__ __forceinline__ uint32_t fkey(float v) {
  uint32_t b = __float_as_uint(v);
  return b ^ ((uint32_t)((int)b >> 31) | 0x80000000u);
}
__device__ __forceinline__ float unkey(uint32_t k) {
  uint32_t b = (k & 0x80000000u) ? (k ^ 0x80000000u) : ~k;
  return __uint_as_float(b);
}
__device__ __forceinline__ ushort f2bf(float v) {  // RNE float->bf16 bits
  uint32_t u = __float_as_uint(v);
  u += 0x7FFFu + ((u >> 16) & 1u);
  return (ushort)(u >> 16);
}
__device__ __forceinline__ float bf2f(ushort h) {
  return __uint_as_float(((uint32_t)h) << 16);
}

// key-only sorted-insert, depth 8: 2 VALU/step
__device__ __forceinline__ void insert8k(uint32_t (&d)[KSEL], uint32_t key) {
#pragma unroll
  for (int r = 0; r < KSEL; ++r) {
    uint32_t nd = min(d[r], key);
    key = max(d[r], key);
    d[r] = nd;
  }
}

// ---------------------------------------------------------------------------
// sq[i] = sum_d x[i][d]^2 ; also track max sq (for the bf16 error margin)
// ---------------------------------------------------------------------------
__global__ void sqnorm_kernel(const float* __restrict__ x, int ldx, int D,
                              float* __restrict__ sq,
                              unsigned int* __restrict__ nmax2u) {
  int i = blockIdx.x * blockDim.x + threadIdx.x;
  if (i >= NPTS) return;
  const float* xr = x + (size_t)i * ldx;
  float s = 0.f;
  for (int d = 0; d < D; ++d) { float v = xr[d]; s += v * v; }
  sq[i] = s;
  atomicMax(nmax2u, __float_as_uint(s));  // s >= 0: uint order == float order
}

// ---------------------------------------------------------------------------
// fp32 x (stride ldx, 64 dims) -> split bf16 planes: xh = bf16(x),
// xl = bf16(x - float(xh)).  dot(h+l, h+l) ~ hh+hl+lh, err <= 2^-17 |x||y|.
// ---------------------------------------------------------------------------
__global__ __launch_bounds__(256) void tobf16_kernel(
    const float* __restrict__ x, int ldx, ushort* __restrict__ xh,
    ushort* __restrict__ xl) {
  const int i = blockIdx.x * 256 + threadIdx.x;  // 65536 threads x 8 vals
  const int row = (i * 8) >> 6, col = (i * 8) & 63;
  const float* src = &x[(size_t)row * ldx + col];
  ushort oh[8], ol[8];
#pragma unroll
  for (int e = 0; e < 8; ++e) {
    float v = src[e];
    ushort h = f2bf(v);
    oh[e] = h;
    ol[e] = f2bf(v - bf2f(h));
  }
  *(ushort4*)&xh[(size_t)row * 64 + col] =
      make_ushort4(oh[0], oh[1], oh[2], oh[3]);
  *(ushort4*)&xh[(size_t)row * 64 + col + 4] =
      make_ushort4(oh[4], oh[5], oh[6], oh[7]);
  *(ushort4*)&xl[(size_t)row * 64 + col] =
      make_ushort4(ol[0], ol[1], ol[2], ol[3]);
  *(ushort4*)&xl[(size_t)row * 64 + col + 4] =
      make_ushort4(ol[4], ol[5], ol[6], ol[7]);
}

// ---------------------------------------------------------------------------
// 64-D keys pass (round-17 config): fused fp32 GEMM + key-only top-8 per
// stream over the QUARTER subset (cands 0..2047). Grid (64 qb, 8 chunks of
// 256), 16 lists, (256,2).
// ---------------------------------------------------------------------------
#define WRITE_S(QR, BASE)                                                   \
  {                                                                         \
    const int cc = (4 * bg) & 31;                                           \
    const int jbase = cb + (QR)*32 + cc;                                    \
    _Pragma("unroll") for (int u = 0; u < 8; ++u) {                         \
      const int row = 4 * am + (u & 3) + 64 * (u >> 2);                     \
      const int gq = qb * 128 + row;                                        \
      const int sw = ((row & 7) ^ ((row >> 2) & 7)) << 2;                   \
      uint32_t k0 = fkey(fmaf(-2.f, acc[u][(BASE) + 0], sc[(BASE) + 0]));   \
      uint32_t k1 = fkey(fmaf(-2.f, acc[u][(BASE) + 1], sc[(BASE) + 1]));   \
      uint32_t k2 = fkey(fmaf(-2.f, acc[u][(BASE) + 2], sc[(BASE) + 2]));   \
      uint32_t k3 = fkey(fmaf(-2.f, acc[u][(BASE) + 3], sc[(BASE) + 3]));   \
      if (jbase + 0 == gq) k0 = 0xFFFFFFFFu;                                \
      if (jbase + 1 == gq) k1 = 0xFFFFFFFFu;                                \
      if (jbase + 2 == gq) k2 = 0xFFFFFFFFu;                                \
      if (jbase + 3 == gq) k3 = 0xFFFFFFFFu;                                \
      *(uint4*)&S[row * 32 + (cc ^ sw)] = make_uint4(k0, k1, k2, k3);       \
    }                                                                       \
  }

#define COMMIT_CS()                                                         \
  {                                                                         \
    Cs[(ck + 0) * 128 + cn] = p0.x;  Cs[(ck + 1) * 128 + cn] = p0.y;        \
    Cs[(ck + 2) * 128 + cn] = p0.z;  Cs[(ck + 3) * 128 + cn] = p0.w;        \
    Cs[(ck + 4) * 128 + cn] = p1.x;  Cs[(ck + 5) * 128 + cn] = p1.y;        \
    Cs[(ck + 6) * 128 + cn] = p1.z;  Cs[(ck + 7) * 128 + cn] = p1.w;        \
    Cs[(ck + 8) * 128 + cn] = p2.x;  Cs[(ck + 9) * 128 + cn] = p2.y;        \
    Cs[(ck + 10) * 128 + cn] = p2.z; Cs[(ck + 11) * 128 + cn] = p2.w;       \
    Cs[(ck + 12) * 128 + cn] = p3.x; Cs[(ck + 13) * 128 + cn] = p3.y;       \
    Cs[(ck + 14) * 128 + cn] = p3.z; Cs[(ck + 15) * 128 + cn] = p3.w;       \
  }

#define ISSUE_CS(BASEROW, KOFF)                                             \
  {                                                                         \
    const float* src_ = &x[(size_t)((BASEROW) + cn) * LDX + (KOFF) + ck];   \
    p0 = *(const float4*)&src_[0];                                          \
    p1 = *(const float4*)&src_[4];                                          \
    p2 = *(const float4*)&src_[8];                                          \
    p3 = *(const float4*)&src_[12];                                         \
  }

template <int LDX>
__global__ __launch_bounds__(256, 2) void knn_gemm_kernel(
    const float* __restrict__ x, const float* __restrict__ sq,
    uint32_t* __restrict__ pk) {
  __shared__ float Qs[64 * 128];      // [k][q]
  __shared__ uint32_t CsS[32 * 128];  // Cs floats during compute; S keys
  float* const Cs = (float*)CsS;
  uint32_t* const S = CsS;
  const int t = threadIdx.x;
  const int qb = blockIdx.x;  // 0..63
  const int ch = blockIdx.y;  // 0..7 (subset cands ch*256 .. +255)
  const int am = t & 15;
  const int bg = (t >> 4) & 15;
  const int cn = t & 127;
  const int ck = (t >> 7) * 16;

  {  // Q stage
    const int q = t & 127;
    const int k0 = (t >> 7) * 32;
    const float* src = &x[(size_t)(qb * 128 + q) * LDX + k0];
#pragma unroll
    for (int c = 0; c < 8; ++c) {
      float4 v = *(const float4*)&src[c * 4];
      Qs[(k0 + c * 4 + 0) * 128 + q] = v.x;
      Qs[(k0 + c * 4 + 1) * 128 + q] = v.y;
      Qs[(k0 + c * 4 + 2) * 128 + q] = v.z;
      Qs[(k0 + c * 4 + 3) * 128 + q] = v.w;
    }
  }

  const int selq = t & 127, part = t >> 7;
  uint32_t dreg[KSEL];
#pragma unroll
  for (int r = 0; r < KSEL; ++r) dreg[r] = 0xFFFFFFFFu;

  float4 p0, p1, p2, p3;
  ISSUE_CS(ch * 256, 0)

#pragma unroll 1
  for (int tile = 0; tile < 2; ++tile) {
    const int cb = ch * 256 + tile * 128;
    float acc[8][8] = {};
#pragma unroll
    for (int kh = 0; kh < 2; ++kh) {
      __syncthreads();
      COMMIT_CS()
      if (kh == 0) {
        ISSUE_CS(cb, 32)
      } else if (tile == 0) {
        ISSUE_CS(cb + 128, 0)
      }
      __syncthreads();
#pragma unroll 4
      for (int k2 = 0; k2 < 32; ++k2) {
        const int k = kh * 32 + k2;
        float4 A0 = *(const float4*)&Qs[k * 128 + 4 * am];
        float4 A1 = *(const float4*)&Qs[k * 128 + 4 * am + 64];
        float4 B0 = *(const float4*)&Cs[k2 * 128 + 4 * bg];
        float4 B1 = *(const float4*)&Cs[k2 * 128 + 4 * bg + 64];
        float a[8] = {A0.x, A0.y, A0.z, A0.w, A1.x, A1.y, A1.z, A1.w};
        float b[8] = {B0.x, B0.y, B0.z, B0.w, B1.x, B1.y, B1.z, B1.w};
#pragma unroll
        for (int u = 0; u < 8; ++u)
#pragma unroll
          for (int v = 0; v < 8; ++v) acc[u][v] = fmaf(a[u], b[v], acc[u][v]);
      }
    }
    float4 s0 = *(const float4*)&sq[cb + 4 * bg];
    float4 s1 = *(const float4*)&sq[cb + 4 * bg + 64];
    float sc[8] = {s0.x, s0.y, s0.z, s0.w, s1.x, s1.y, s1.z, s1.w};

    const int qlow = bg >> 3;
    for (int qr = 0; qr < 4; ++qr) {
      __syncthreads();
      if (qr == qlow) WRITE_S(qr, 0);
      if (qr == 2 + qlow) WRITE_S(qr, 4);
      __syncthreads();
      const int swr = ((selq & 7) ^ ((selq >> 2) & 7)) << 2;
#pragma unroll
      for (int g_ = 0; g_ < 4; ++g_) {
        const int cc = part * 16 + g_ * 4;
        uint4 sv = *(const uint4*)&S[selq * 32 + (cc ^ swr)];
        uint32_t kv[4] = {sv.x, sv.y, sv.z, sv.w};
#pragma unroll
        for (int e = 0; e < 4; ++e) {
          if (kv[e] < dreg[KSEL - 1]) insert8k(dreg, kv[e]);
        }
      }
    }
  }
  const int l = ch * 2 + part;  // 16 lists
  uint32_t* pkq = pk + ((size_t)l * NPTS + (qb * 128 + selq)) * KSEL;
#pragma unroll
  for (int r = 0; r < KSEL; ++r) pkq[r] = dreg[r];
}

// ---------------------------------------------------------------------------
// Tournament over 16 sorted 8-entry key-lists -> Tf[q] = 20th distance of
// the union + mscale*sqrt(sq_q * max_j sq_j). mscale=0 for the exact d3
// path; 1e-4 for the split-bf16 filter (error bound 2^-17, 13x headroom).
// ---------------------------------------------------------------------------
__global__ __launch_bounds__(256) void knn_mergeT_kernel(
    const uint32_t* __restrict__ pk, const float* __restrict__ sq,
    const float* __restrict__ nmax2, float* __restrict__ Tf, float mscale) {
  __shared__ uint32_t sk[16][16][KSEL];
  const int t = threadIdx.x;
  const int ql = t >> 4;
  const int l = t & 15;
  const int q = blockIdx.x * 16 + ql;
  const uint32_t* pkq = pk + ((size_t)l * NPTS + q) * KSEL;
#pragma unroll
  for (int r = 0; r < KSEL; ++r) sk[ql][l][r] = pkq[r];
  __syncthreads();
  int ptr = 0;
  uint32_t k = 0;
#pragma unroll 1
  for (int s = 0; s < KNN; ++s) {
    k = (ptr < KSEL) ? sk[ql][l][ptr] : 0xFFFFFFFFu;
    int src = l;
#pragma unroll
    for (int off = 8; off >= 1; off >>= 1) {
      uint32_t ok = __shfl_xor(k, off, 16);
      int osrc = __shfl_xor(src, off, 16);
      bool take = (ok < k) || (ok == k && osrc < src);
      k = take ? ok : k;
      src = take ? osrc : src;
    }
    if (l == src) ptr++;
  }
  if (l == 0) Tf[q] = unkey(k) + mscale * sqrtf(sq[q] * nmax2[0]);
}

// ---------------------------------------------------------------------------
// 64-D MFMA recover, split-bf16. ROUND-21: coalesced LDS staging of the
// fragment tiles. Rounds 17-20 showed dur pinned at 105us invariant to
// occupancy (28->47%) and tile shape -- the shared bound was ~33M scattered
// 16B global fragment loads pulling full lines at <=50% utilization (~1-2GB
// effective L2 traffic). Now the block stages A (128x64x2 planes) + B
// (64x64x2) with fully coalesced 16B loads (48 KB/block, zero redundancy),
// fragments come from ds_read_b128 (row stride 144B: 16B-aligned, 4-way
// bank conflict = 1.58x, acceptable). Fragment values bit-identical.
// LDS 63.5 KB -> 2 blocks/CU (occupancy proven irrelevant in r20).
// ---------------------------------------------------------------------------
__global__ __launch_bounds__(256, 2) void knn_recover_mfma_kernel(
    const ushort* __restrict__ xh, const ushort* __restrict__ xl,
    const float* __restrict__ sq, const float* __restrict__ Tf,
    uint32_t* __restrict__ cnt, int* __restrict__ cj) {
  __shared__ ushort Ah_s[128 * 72];  // 18.4 KB, row stride 144B
  __shared__ ushort Al_s[128 * 72];  // 18.4 KB
  __shared__ ushort Bh_s[64 * 72];   // 9.2 KB
  __shared__ ushort Bl_s[64 * 72];   // 9.2 KB
  __shared__ uint32_t nsurv;
  __shared__ uint2 surv[LCAPM];      // 8 KB
  const int t = threadIdx.x;
  const int w = t >> 6, l = t & 63;
  const int qbase = blockIdx.x * 128;
  const int cbase = blockIdx.y * 64;
  const int q0 = qbase + w * 32;  // wave's 32 query rows
  const int lr = l & 31;
  const int ko = (l >> 5) * 8;
  const int rowbase = (l >> 5) * 4;

  if (t == 0) nsurv = 0;

  {  // stage A: 128 rows x 128B x 2 planes, fully coalesced
    const int row = t >> 1, half = t & 1;
    const uint4* sh = (const uint4*)&xh[(size_t)(qbase + row) * 64 + half * 32];
    const uint4* sl = (const uint4*)&xl[(size_t)(qbase + row) * 64 + half * 32];
    uint4* dh = (uint4*)&Ah_s[row * 72 + half * 32];
    uint4* dl = (uint4*)&Al_s[row * 72 + half * 32];
#pragma unroll
    for (int i = 0; i < 4; ++i) { dh[i] = sh[i]; dl[i] = sl[i]; }
  }
  {  // stage B: 64 rows x 128B x 2 planes (threads 0-127: h, 128-255: l)
    const int pl = t >> 7;
    const int rr = (t & 127) >> 1, half = t & 1;
    const ushort* src = pl ? xl : xh;
    ushort* dst = pl ? Bl_s : Bh_s;
    const uint4* s = (const uint4*)&src[(size_t)(cbase + rr) * 64 + half * 32];
    uint4* d = (uint4*)&dst[rr * 72 + half * 32];
#pragma unroll
    for (int i = 0; i < 4; ++i) d[i] = s[i];
  }

  // preload thresholds for the 16 output rows this lane touches
  float tq[16];
#pragma unroll
  for (int r = 0; r < 16; ++r)
    tq[r] = Tf[q0 + (r & 3) + 8 * (r >> 2) + rowbase];

  __syncthreads();  // staging + nsurv visible

  f32x16 acc[2] = {};
#pragma unroll
  for (int kk = 0; kk < 4; ++kk) {
    const int cu = kk * 16 + ko;  // ushort column
    bf16x8 Ah, Al, Bh[2], Bl[2];
    {
      const int row = w * 32 + lr;
      Ah = *(const bf16x8*)&Ah_s[row * 72 + cu];
      Al = *(const bf16x8*)&Al_s[row * 72 + cu];
    }
#pragma unroll
    for (int ct = 0; ct < 2; ++ct) {
      const int row = ct * 32 + lr;
      Bh[ct] = *(const bf16x8*)&Bh_s[row * 72 + cu];
      Bl[ct] = *(const bf16x8*)&Bl_s[row * 72 + cu];
    }
#pragma unroll
    for (int ct = 0; ct < 2; ++ct) {
      acc[ct] = __builtin_amdgcn_mfma_f32_32x32x16_bf16(Ah, Bh[ct], acc[ct],
                                                        0, 0, 0);
      acc[ct] = __builtin_amdgcn_mfma_f32_32x32x16_bf16(Ah, Bl[ct], acc[ct],
                                                        0, 0, 0);
      acc[ct] = __builtin_amdgcn_mfma_f32_32x32x16_bf16(Al, Bh[ct], acc[ct],
                                                        0, 0, 0);
    }
  }

#pragma unroll
  for (int ct = 0; ct < 2; ++ct) {
    const int j = cbase + ct * 32 + lr;
    const float sqj = sq[j];
#pragma unroll
    for (int r = 0; r < 16; ++r) {
      const int gq = q0 + (r & 3) + 8 * (r >> 2) + rowbase;
      float d = fmaf(-2.f, acc[ct][r], sqj);
      if (j != gq && d <= tq[r]) {
        uint32_t idx = atomicAdd(&nsurv, 1u);  // LDS atomic, fast
        if (idx < (uint32_t)LCAPM) {
          surv[idx] = make_uint2((uint32_t)gq, (uint32_t)j);
        } else {  // overflow fallback: direct append
          uint32_t slot = atomicAdd(&cnt[gq], 1u);
          if (slot < (uint32_t)CAP64) cj[(size_t)gq * CAP64 + slot] = j;
        }
      }
    }
  }
  __syncthreads();
  const uint32_t nv = min(nsurv, (uint32_t)LCAPM);
#pragma unroll 1
  for (uint32_t i = t; i < nv; i += 256) {
    uint2 e = surv[i];
    uint32_t slot = atomicAdd(&cnt[e.x], 1u);
    if (slot < (uint32_t)CAP64) cj[(size_t)e.x * CAP64 + slot] = (int)e.y;
  }
}

// ---------------------------------------------------------------------------
// 64-D final: exact fp32 re-rank of <=CAP64 survivors. One wave per query.
// ---------------------------------------------------------------------------
template <int LDX>
__global__ __launch_bounds__(256) void knn_final64_kernel(
    const float* __restrict__ x, const float* __restrict__ sq,
    const uint32_t* __restrict__ cnt, const int* __restrict__ cj,
    int* __restrict__ idx_out) {
  __shared__ float xqs[4][64];
  const int t = threadIdx.x, w = t >> 6, l = t & 63;
  const int q = blockIdx.x * 4 + w;
  if (l < 16)
    *(float4*)&xqs[w][l * 4] = *(const float4*)&x[(size_t)q * LDX + l * 4];
  __syncthreads();
  const int n = (int)min(cnt[q], (uint32_t)CAP64);
  uint32_t ks[8]; int js[8];
#pragma unroll
  for (int r = 0; r < 8; ++r) { ks[r] = 0xFFFFFFFFu; js[r] = 0x7fffffff; }
#pragma unroll 1
  for (int it = 0; it < 8; ++it) {
    const int c = l + it * 64;
    if (c < n) {
      const int j = cj[(size_t)q * CAP64 + c];
      const float* xj = &x[(size_t)j * LDX];
      float dot = 0.f;
#pragma unroll
      for (int e = 0; e < 16; ++e) {
        float4 a = *(const float4*)&xj[e * 4];
        float4 b = *(const float4*)&xqs[w][e * 4];
        dot = fmaf(a.x, b.x, dot);
        dot = fmaf(a.y, b.y, dot);
        dot = fmaf(a.z, b.z, dot);
        dot = fmaf(a.w, b.w, dot);
      }
      float d = fmaf(-2.f, dot, sq[j]);
      uint32_t ck = fkey(d);
      int ci = j;
#pragma unroll
      for (int r = 0; r < 8; ++r) {  // tie-aware sorted insert
        bool sw = (ck < ks[r]) || (ck == ks[r] && ci < js[r]);
        uint32_t ok = ks[r]; int oj = js[r];
        ks[r] = sw ? ck : ok; js[r] = sw ? ci : oj;
        ck = sw ? ok : ck; ci = sw ? oj : ci;
      }
    }
  }
#pragma unroll 1
  for (int s = 0; s < KNN; ++s) {
    uint32_t mk = ks[0];
    int mj = js[0];
#pragma unroll
    for (int off = 32; off >= 1; off >>= 1) {
      uint32_t ok = __shfl_xor(mk, off, 64);
      int oj = __shfl_xor(mj, off, 64);
      bool take = (ok < mk) || (ok == mk && oj < mj);
      mk = take ? ok : mk;
      mj = take ? oj : mj;
    }
    if (ks[0] == mk && js[0] == mj) {  // j unique per query -> unique winner
#pragma unroll
      for (int r = 0; r < 7; ++r) { ks[r] = ks[r + 1]; js[r] = js[r + 1]; }
      ks[7] = 0xFFFFFFFFu; js[7] = 0x7fffffff;
    }
    if (l == 0) idx_out[(size_t)q * KNN + s] = mj;
  }
}

// ---------------------------------------------------------------------------
// 3-D approx pass: key-only top-8 over QUARTER subset (cands 0..2047).
// ---------------------------------------------------------------------------
__global__ __launch_bounds__(256) void knn_d3k_kernel(
    const float* __restrict__ x, const float* __restrict__ sq,
    uint32_t* __restrict__ pk) {
  __shared__ float4 Ct[128];
  const int t = threadIdx.x;
  const int q = blockIdx.x * 256 + t;
  const int ch = blockIdx.y;  // 0..15
  const int cb = ch * 128;
  if (t < 128)
    Ct[t] = make_float4(x[(cb + t) * 3], x[(cb + t) * 3 + 1],
                        x[(cb + t) * 3 + 2], sq[cb + t]);
  const float xi0 = x[q * 3], xi1 = x[q * 3 + 1], xi2 = x[q * 3 + 2];
  uint32_t dreg[KSEL];
#pragma unroll
  for (int r = 0; r < KSEL; ++r) dreg[r] = 0xFFFFFFFFu;
  __syncthreads();
#pragma unroll 1
  for (int c = 0; c < 128; ++c) {
    float4 cv = Ct[c];
    int j = cb + c;
    float val = fmaf(-2.f, xi0 * cv.x + xi1 * cv.y + xi2 * cv.z, cv.w);
    uint32_t key = fkey(val);
    if (j != q && key < dreg[KSEL - 1]) insert8k(dreg, key);
  }
  uint32_t* pkq = pk + ((size_t)ch * NPTS + q) * KSEL;
#pragma unroll
  for (int r = 0; r < KSEL; ++r) pkq[r] = dreg[r];
}

// ---------------------------------------------------------------------------
// 3-D recovery: stream all 8192 candidates, compact d <= Tf.
// Two-level LDS survivor append (round 17).
// ---------------------------------------------------------------------------
__global__ __launch_bounds__(256) void knn_d3_recover_kernel(
    const float* __restrict__ x, const float* __restrict__ sq,
    const float* __restrict__ Tf, uint32_t* __restrict__ cnt,
    uint32_t* __restrict__ cd, int* __restrict__ cj) {
  __shared__ float4 Ct[256];
  __shared__ uint32_t nsurv;
  __shared__ uint2 surv[LCAP];  // 16 KB
  const int t = threadIdx.x;
  const int q0 = blockIdx.x * 256;
  const int q = q0 + t;
  const int cb = blockIdx.y * 256;
  if (t == 0) nsurv = 0;
  Ct[t] = make_float4(x[(cb + t) * 3], x[(cb + t) * 3 + 1],
                      x[(cb + t) * 3 + 2], sq[cb + t]);
  const float xi0 = x[q * 3], xi1 = x[q * 3 + 1], xi2 = x[q * 3 + 2];
  const float Tq = Tf[q];
  __syncthreads();  // covers Ct + nsurv
#pragma unroll 1
  for (int c = 0; c < 256; ++c) {
    float4 cv = Ct[c];
    int j = cb + c;
    float val = fmaf(-2.f, xi0 * cv.x + xi1 * cv.y + xi2 * cv.z, cv.w);
    if (j != q && val <= Tq) {
      uint32_t idx = atomicAdd(&nsurv, 1u);  // LDS atomic
      if (idx < (uint32_t)LCAP) {
        surv[idx] = make_uint2(fkey(val), ((uint32_t)t << 16) | (uint32_t)j);
      } else {  // overflow fallback
        uint32_t slot = atomicAdd(&cnt[q], 1u);
        if (slot < (uint32_t)CAPD3) {
          cd[(size_t)q * CAPD3 + slot] = fkey(val);
          cj[(size_t)q * CAPD3 + slot] = j;
        }
      }
    }
  }
  __syncthreads();
  const uint32_t nv = min(nsurv, (uint32_t)LCAP);
#pragma unroll 1
  for (uint32_t i = t; i < nv; i += 256) {
    uint2 e = surv[i];
    const int qq = q0 + (int)(e.y >> 16);
    const int jj = (int)(e.y & 0xFFFFu);
    uint32_t slot = atomicAdd(&cnt[qq], 1u);
    if (slot < (uint32_t)CAPD3) {
      cd[(size_t)qq * CAPD3 + slot] = e.x;
      cj[(size_t)qq * CAPD3 + slot] = jj;
    }
  }
}

// ---------------------------------------------------------------------------
// d3 final select (exact keys in cd): one wave per query, 4/lane + tournament.
// ---------------------------------------------------------------------------
#define CSWAP(ka, ja, kb, jb)                                   \
  {                                                             \
    bool sw = (kb < ka) || (kb == ka && jb < ja);               \
    uint32_t tk = sw ? kb : ka; int tj = sw ? jb : ja;          \
    kb = sw ? ka : kb; jb = sw ? ja : jb;                       \
    ka = tk; ja = tj;                                           \
  }

__global__ __launch_bounds__(256) void knn_final_d3_kernel(
    const uint32_t* __restrict__ cnt, const uint32_t* __restrict__ cd,
    const int* __restrict__ cj, int* __restrict__ idx_out) {
  const int t = threadIdx.x;
  const int w = t >> 6;
  const int l = t & 63;
  const int q = blockIdx.x * 4 + w;
  const int n = (int)min(cnt[q], (uint32_t)CAPD3);
  uint32_t k0 = 0xFFFFFFFFu, k1 = 0xFFFFFFFFu, k2 = 0xFFFFFFFFu,
           k3 = 0xFFFFFFFFu;
  int j0 = 0x7fffffff, j1 = 0x7fffffff, j2 = 0x7fffffff, j3 = 0x7fffffff;
  if (l < n) { k0 = cd[(size_t)q * CAPD3 + l]; j0 = cj[(size_t)q * CAPD3 + l]; }
  if (l + 64 < n) { k1 = cd[(size_t)q * CAPD3 + l + 64]; j1 = cj[(size_t)q * CAPD3 + l + 64]; }
  if (l + 128 < n) { k2 = cd[(size_t)q * CAPD3 + l + 128]; j2 = cj[(size_t)q * CAPD3 + l + 128]; }
  if (l + 192 < n) { k3 = cd[(size_t)q * CAPD3 + l + 192]; j3 = cj[(size_t)q * CAPD3 + l + 192]; }
  CSWAP(k0, j0, k1, j1); CSWAP(k2, j2, k3, j3);
  CSWAP(k0, j0, k2, j2); CSWAP(k1, j1, k3, j3);
  CSWAP(k1, j1, k2, j2);
#pragma unroll 1
  for (int s = 0; s < KNN; ++s) {
    uint32_t mk = k0;
    int mj = j0;
#pragma unroll
    for (int off = 32; off >= 1; off >>= 1) {
      uint32_t ok = __shfl_xor(mk, off, 64);
      int oj = __shfl_xor(mj, off, 64);
      bool take = (ok < mk) || (ok == mk && oj < mj);
      mk = take ? ok : mk;
      mj = take ? oj : mj;
    }
    if (k0 == mk && j0 == mj) {
      k0 = k1; j0 = j1; k1 = k2; j1 = j2; k2 = k3; j2 = j3;
      k3 = 0xFFFFFFFFu; j3 = 0x7fffffff;
    }
    if (l == 0) idx_out[(size_t)q * KNN + s] = mj;
  }
}

// ---------------------------------------------------------------------------
// edge conv (unchanged)
// ---------------------------------------------------------------------------
__global__ __launch_bounds__(256) void edgeconv_kernel(
    const float* __restrict__ x, const int* __restrict__ idx,
    const float* __restrict__ W1, const float* __restrict__ b1,
    float* __restrict__ out) {
  const int i = blockIdx.x * 4 + (threadIdx.x >> 6);
  const int c = threadIdx.x & 63;
  float w0 = W1[c], w1 = W1[64 + c], w2 = W1[128 + c];
  float w3 = W1[192 + c], w4 = W1[256 + c], w5 = W1[320 + c];
  float xi0 = x[3 * i], xi1 = x[3 * i + 1], xi2 = x[3 * i + 2];
  float base = b1[c] + xi0 * w0 + xi1 * w1 + xi2 * w2;
  float m = -INFINITY;
#pragma unroll
  for (int k = 0; k < KNN; ++k) {
    int j = idx[i * KNN + k];
    float d0 = x[3 * j] - xi0, d1 = x[3 * j + 1] - xi1, d2 = x[3 * j + 2] - xi2;
    float h = base + d0 * w3 + d1 * w4 + d2 * w5;
    m = fmaxf(m, fmaxf(h, 0.f));
  }
  out[(size_t)i * 64 + c] = m;
}

// ---------------------------------------------------------------------------
// dilate (unchanged)
// ---------------------------------------------------------------------------
__global__ __launch_bounds__(256) void dilate_kernel(
    const float* __restrict__ xin, int ldin, const int* __restrict__ idx,
    const float* __restrict__ W, const float* __restrict__ bias,
    float* __restrict__ out, int ldout) {
  const int g = threadIdx.x >> 6;
  const int i = blockIdx.x * 4 + g;
  const int c = threadIdx.x & 63;
  __shared__ float dil[4][64];
  float m = -INFINITY;
#pragma unroll
  for (int k = 0; k < KNN; ++k) {
    int j = idx[i * KNN + k];
    m = fmaxf(m, xin[(size_t)j * ldin + c]);
  }
  dil[g][c] = m;
  __syncthreads();
  float acc = bias[c];
#pragma unroll
  for (int d = 0; d < 64; ++d) acc = fmaf(dil[g][d], W[d * 64 + c], acc);
  out[(size_t)i * ldout + c] = fmaxf(acc, 0.f) - xin[(size_t)i * ldin + c];
}

// ---------------------------------------------------------------------------
// BM=128 x BN tile fp32 GEMM with T14 register double-buffer (round 17).
// ---------------------------------------------------------------------------
template <int BN>
__global__ __launch_bounds__(256) void gemm128_kernel(
    const float* __restrict__ A, int K, int ldA, const float* __restrict__ W,
    int N, const float* __restrict__ bias, float* __restrict__ C, int ldC,
    int relu) {
  constexpr int VN = BN / 16;
  __shared__ float As[16 * 128];
  __shared__ float Bs[16 * BN];
  const int t = threadIdx.x;
  const int bn = blockIdx.x * BN;
  const int bm = blockIdx.y * 128;
  const int am = t & 15;
  const int bg = (t >> 4) & 15;
  const int m_ = t & 127;          // A staging row
  const int ka = (t >> 7) * 8;     // A staging k-base
  const int kb = t >> 4;           // B staging k-row
  const int nb = (t & 15) * (BN == 128 ? 8 : 4);  // B staging col
  float acc[8][VN] = {};
  float4 av0, av1, bv0, bv1;

  {  // issue k0 = 0
    const float* srcA = &A[(size_t)(bm + m_) * ldA + ka];
    av0 = *(const float4*)&srcA[0];
    av1 = *(const float4*)&srcA[4];
    const float* srcB = &W[(size_t)kb * N + bn + nb];
    bv0 = *(const float4*)&srcB[0];
    if constexpr (BN == 128) bv1 = *(const float4*)&srcB[4];
  }

  for (int k0 = 0; k0 < K; k0 += 16) {
    __syncthreads();  // prev compute done -> LDS reusable
    As[(ka + 0) * 128 + m_] = av0.x;
    As[(ka + 1) * 128 + m_] = av0.y;
    As[(ka + 2) * 128 + m_] = av0.z;
    As[(ka + 3) * 128 + m_] = av0.w;
    As[(ka + 4) * 128 + m_] = av1.x;
    As[(ka + 5) * 128 + m_] = av1.y;
    As[(ka + 6) * 128 + m_] = av1.z;
    As[(ka + 7) * 128 + m_] = av1.w;
    *(float4*)&Bs[kb * BN + nb] = bv0;
    if constexpr (BN == 128) *(float4*)&Bs[kb * BN + nb + 4] = bv1;
    if (k0 + 16 < K) {  // issue next K-step (hides under compute below)
      const float* srcA = &A[(size_t)(bm + m_) * ldA + k0 + 16 + ka];
      av0 = *(const float4*)&srcA[0];
      av1 = *(const float4*)&srcA[4];
      const float* srcB = &W[(size_t)(k0 + 16 + kb) * N + bn + nb];
      bv0 = *(const float4*)&srcB[0];
      if constexpr (BN == 128) bv1 = *(const float4*)&srcB[4];
    }
    __syncthreads();
#pragma unroll
    for (int k = 0; k < 16; ++k) {
      float4 A0 = *(const float4*)&As[k * 128 + 4 * am];
      float4 A1 = *(const float4*)&As[k * 128 + 4 * am + 64];
      float a[8] = {A0.x, A0.y, A0.z, A0.w, A1.x, A1.y, A1.z, A1.w};
      float b[VN];
      float4 B0 = *(const float4*)&Bs[k * BN + 4 * bg];
      b[0] = B0.x; b[1] = B0.y; b[2] = B0.z; b[3] = B0.w;
      if constexpr (BN == 128) {
        float4 B1 = *(const float4*)&Bs[k * BN + 4 * bg + 64];
        b[4] = B1.x; b[5] = B1.y; b[6] = B1.z; b[7] = B1.w;
      }
#pragma unroll
      for (int u = 0; u < 8; ++u)
#pragma unroll
        for (int v = 0; v < VN; ++v) acc[u][v] = fmaf(a[u], b[v], acc[u][v]);
    }
  }
#pragma unroll
  for (int u = 0; u < 8; ++u) {
    const int m = bm + 4 * am + (u & 3) + 64 * (u >> 2);
#pragma unroll
    for (int vq = 0; vq < VN / 4; ++vq) {
      const int n = bn + 4 * bg + 64 * vq;
      float4 o;
      float* po = (float*)&o;
#pragma unroll
      for (int e = 0; e < 4; ++e) {
        float val = acc[u][vq * 4 + e] + bias[n + e];
        po[e] = relu ? fmaxf(val, 0.f) : val;
      }
      *(float4*)&C[(size_t)m * ldC + n] = o;
    }
  }
}

// ---------------------------------------------------------------------------
// logits + log_softmax (unchanged)
// ---------------------------------------------------------------------------
__global__ __launch_bounds__(256) void final_kernel(
    const float* __restrict__ h3, const float* __restrict__ Wm3,
    const float* __restrict__ bm3, float* __restrict__ out) {
  __shared__ float hs[16][132];
  const int tid = threadIdx.x;
  const int r = tid >> 4, c = tid & 15;
  const int row0 = blockIdx.x * 16;
#pragma unroll
  for (int l = tid; l < 2048; l += 256)
    hs[l >> 7][l & 127] = h3[(size_t)row0 * 128 + l];
  __syncthreads();
  float acc = bm3[c];
#pragma unroll
  for (int d = 0; d < 128; ++d) acc = fmaf(hs[r][d], Wm3[d * 16 + c], acc);
  float mx = acc;
#pragma unroll
  for (int o = 8; o >= 1; o >>= 1) mx = fmaxf(mx, __shfl_xor(mx, o, 16));
  float e = expf(acc - mx);
  float s = e;
#pragma unroll
  for (int o = 8; o >= 1; o >>= 1) s += __shfl_xor(s, o, 16);
  out[(size_t)(row0 + r) * 16 + c] = (acc - mx) - logf(s);
}

// ---------------------------------------------------------------------------
extern "C" void kernel_launch(void* const* d_in, const int* in_sizes, int n_in,
                              void* d_out, int out_size, void* d_ws,
                              size_t ws_size, hipStream_t stream) {
  const float* x = (const float*)d_in[0];
  const float* W1 = (const float*)d_in[1];
  const float* b1 = (const float*)d_in[2];
  const float* Wd1 = (const float*)d_in[3];
  const float* bd1 = (const float*)d_in[4];
  const float* Wd2 = (const float*)d_in[5];
  const float* bd2 = (const float*)d_in[6];
  const float* Wd3 = (const float*)d_in[7];
  const float* bd3 = (const float*)d_in[8];
  const float* Wl = (const float*)d_in[9];
  const float* bl = (const float*)d_in[10];
  const float* Wm1 = (const float*)d_in[11];
  const float* bm1 = (const float*)d_in[12];
  const float* Wm2 = (const float*)d_in[13];
  const float* bm2 = (const float*)d_in[14];
  const float* Wm3 = (const float*)d_in[15];
  const float* bm3 = (const float*)d_in[16];
  float* out = (float*)d_out;

  char* ws = (char*)d_ws;
  float* sq = (float*)(ws + 0);              // 32 KB
  int* idxA = (int*)(ws + 32768);            // 640 KB
  float* xfeat = (float*)(ws + 1343488);     // 2 MB   [8192 x 64]
  float* xcat = (float*)(ws + 3440640);      // 6 MB   [8192 x 192]
  float* h1 = (float*)(ws + 9732096);        // 32 MB  [8192 x 1024]
  float* h2 = (float*)(ws + 43286528);       // 8 MB   [8192 x 256]
  float* h3 = (float*)(ws + 51675136);       // 4 MB   [8192 x 128]
  float* x1 = xcat;
  float* x2 = xcat + 64;
  float* x3 = xcat + 128;
  // knn scratch in the h1/h2 region (free until the head GEMMs):
  uint32_t* pk = (uint32_t*)(ws + 9732096);       // 4.19 MB -> 13926400
  uint32_t* cdD3 = (uint32_t*)(ws + 13926400);    // 8.39 MB -> 22315008
  int* cjD3 = (int*)(ws + 22315008);              // 8.39 MB -> 30703616
  float* Tf = (float*)(ws + 30703616);            // 32 KB   -> 30736384
  uint32_t* cnt = (uint32_t*)(ws + 30736384);     // 32 KB   -> 30769152
  unsigned int* nmax2u = (unsigned int*)(ws + 30769152);  // 64 B pad
  float* nmax2f = (float*)nmax2u;
  int* cj64 = (int*)(ws + 30769216);              // 16.78 MB -> 47546432
  ushort* xh = (ushort*)(ws + 47546432);          // 1 MB    -> 48595008
  ushort* xl = (ushort*)(ws + 48595008);          // 1 MB    -> 49643584

  // stage 1: edge conv on xyz (exact-key d3 path, margin 0)
  hipMemsetAsync(cnt, 0, 32768 + 64, stream);  // cnt + nmax2
  sqnorm_kernel<<<32, 256, 0, stream>>>(x, 3, 3, sq, nmax2u);
  knn_d3k_kernel<<<dim3(32, 16), 256, 0, stream>>>(x, sq, pk);
  knn_mergeT_kernel<<<NPTS / 16, 256, 0, stream>>>(pk, sq, nmax2f, Tf, 0.f);
  knn_d3_recover_kernel<<<dim3(32, 32), 256, 0, stream>>>(x, sq, Tf, cnt,
                                                          cdD3, cjD3);
  knn_final_d3_kernel<<<NPTS / 4, 256, 0, stream>>>(cnt, cdD3, cjD3, idxA);
  edgeconv_kernel<<<NPTS / 4, 256, 0, stream>>>(x, idxA, W1, b1, xfeat);

  // stage 2: three dilate blocks; 64-D kNN = fp32 quarter-subset threshold +
  // split-bf16 MFMA conservative filter (margin 1e-4) + exact fp32 re-rank
#define KNN64_PASS(XIN, LDX)                                                  \
  hipMemsetAsync(cnt, 0, 32768 + 64, stream);                                 \
  sqnorm_kernel<<<32, 256, 0, stream>>>(XIN, LDX, 64, sq, nmax2u);            \
  tobf16_kernel<<<256, 256, 0, stream>>>(XIN, LDX, xh, xl);                   \
  knn_gemm_kernel<LDX><<<dim3(64, 8), 256, 0, stream>>>(XIN, sq, pk);         \
  knn_mergeT_kernel<<<NPTS / 16, 256, 0, stream>>>(pk, sq, nmax2f, Tf,        \
                                                   1e-4f);                    \
  knn_recover_mfma_kernel<<<dim3(64, 128), 256, 0, stream>>>(xh, xl, sq, Tf,  \
                                                             cnt, cj64);      \
  knn_final64_kernel<LDX><<<NPTS / 4, 256, 0, stream>>>(XIN, sq, cnt, cj64,   \
                                                        idxA);

  KNN64_PASS(xfeat, 64)
  dilate_kernel<<<NPTS / 4, 256, 0, stream>>>(xfeat, 64, idxA, Wd1, bd1, x1,
                                              192);
  KNN64_PASS(x1, 192)
  dilate_kernel<<<NPTS / 4, 256, 0, stream>>>(x1, 192, idxA, Wd2, bd2, x2,
                                              192);
  KNN64_PASS(x2, 192)
  dilate_kernel<<<NPTS / 4, 256, 0, stream>>>(x2, 192, idxA, Wd3, bd3, x3,
                                              192);
#undef KNN64_PASS

  // stage 3: MLP head
  gemm128_kernel<128><<<dim3(1024 / 128, NPTS / 128), 256, 0, stream>>>(
      xcat, 192, 192, Wl, 1024, bl, h1, 1024, 1);
  gemm128_kernel<64><<<dim3(256 / 64, NPTS / 128), 256, 0, stream>>>(
      h1, 1024, 1024, Wm1, 256, bm1, h2, 256, 1);
  gemm128_kernel<64><<<dim3(128 / 64, NPTS / 128), 256, 0, stream>>>(
      h2, 256, 256, Wm2, 128, bm2, h3, 128, 1);
  final_kernel<<<NPTS / 16, 256, 0, stream>>>(h3, Wm3, bm3, out);
}

// Round 22
// 915.490 us; speedup vs baseline: 1.0018x; 1.0018x over previous
//
#include <hip/hip_runtime.h>
#include <math.h>

#define NPTS 8192
#define KNN 20
#define KSEL 8    // per-stream ripple depth; subset-20th stays an upper bound
#define CAPD3 256 // d3 survivor cap (exact-key path)
#define CAP64 512 // 64-D survivor cap (split-bf16 filter path)
#define LCAP 2048 // d3 per-block LDS survivor list
#define LCAPR 1024 // recover_mfma per-block list (mean ~640, cap+fallback)

typedef __attribute__((ext_vector_type(8))) short bf16x8;
typedef __attribute__((ext_vector_type(16))) float f32x16;

// monotonic u32 key: a<b (float, incl. inf) <=> fkey(a)<fkey(b)
__device__ __forceinline__ uint32_t fkey(float v) {
  uint32_t b = __float_as_uint(v);
  return b ^ ((uint32_t)((int)b >> 31) | 0x80000000u);
}
__device__ __forceinline__ float unkey(uint32_t k) {
  uint32_t b = (k & 0x80000000u) ? (k ^ 0x80000000u) : ~k;
  return __uint_as_float(b);
}
__device__ __forceinline__ ushort f2bf(float v) {  // RNE float->bf16 bits
  uint32_t u = __float_as_uint(v);
  u += 0x7FFFu + ((u >> 16) & 1u);
  return (ushort)(u >> 16);
}
__device__ __forceinline__ float bf2f(ushort h) {
  return __uint_as_float(((uint32_t)h) << 16);
}

// key-only sorted-insert, depth 8: 2 VALU/step
__device__ __forceinline__ void insert8k(uint32_t (&d)[KSEL], uint32_t key) {
#pragma unroll
  for (int r = 0; r < KSEL; ++r) {
    uint32_t nd = min(d[r], key);
    key = max(d[r], key);
    d[r] = nd;
  }
}

// ---------------------------------------------------------------------------
// sq[i] = sum_d x[i][d]^2 ; also track max sq (for the bf16 error margin)
// ---------------------------------------------------------------------------
__global__ void sqnorm_kernel(const float* __restrict__ x, int ldx, int D,
                              float* __restrict__ sq,
                              unsigned int* __restrict__ nmax2u) {
  int i = blockIdx.x * blockDim.x + threadIdx.x;
  if (i >= NPTS) return;
  const float* xr = x + (size_t)i * ldx;
  float s = 0.f;
  for (int d = 0; d < D; ++d) { float v = xr[d]; s += v * v; }
  sq[i] = s;
  atomicMax(nmax2u, __float_as_uint(s));  // s >= 0: uint order == float order
}

// ---------------------------------------------------------------------------
// fp32 x (stride ldx, 64 dims) -> split bf16 planes: xh = bf16(x),
// xl = bf16(x - float(xh)).  dot(h+l, h+l) ~ hh+hl+lh, err <= 2^-17 |x||y|.
// ---------------------------------------------------------------------------
__global__ __launch_bounds__(256) void tobf16_kernel(
    const float* __restrict__ x, int ldx, ushort* __restrict__ xh,
    ushort* __restrict__ xl) {
  const int i = blockIdx.x * 256 + threadIdx.x;  // 65536 threads x 8 vals
  const int row = (i * 8) >> 6, col = (i * 8) & 63;
  const float* src = &x[(size_t)row * ldx + col];
  ushort oh[8], ol[8];
#pragma unroll
  for (int e = 0; e < 8; ++e) {
    float v = src[e];
    ushort h = f2bf(v);
    oh[e] = h;
    ol[e] = f2bf(v - bf2f(h));
  }
  *(ushort4*)&xh[(size_t)row * 64 + col] =
      make_ushort4(oh[0], oh[1], oh[2], oh[3]);
  *(ushort4*)&xh[(size_t)row * 64 + col + 4] =
      make_ushort4(oh[4], oh[5], oh[6], oh[7]);
  *(ushort4*)&xl[(size_t)row * 64 + col] =
      make_ushort4(ol[0], ol[1], ol[2], ol[3]);
  *(ushort4*)&xl[(size_t)row * 64 + col + 4] =
      make_ushort4(ol[4], ol[5], ol[6], ol[7]);
}

// ---------------------------------------------------------------------------
// 64-D keys pass (round-17 config): fused fp32 GEMM + key-only top-8 per
// stream over the QUARTER subset (cands 0..2047). Grid (64 qb, 8 chunks of
// 256), 16 lists, (256,2).
// ---------------------------------------------------------------------------
#define WRITE_S(QR, BASE)                                                   \
  {                                                                         \
    const int cc = (4 * bg) & 31;                                           \
    const int jbase = cb + (QR)*32 + cc;                                    \
    _Pragma("unroll") for (int u = 0; u < 8; ++u) {                         \
      const int row = 4 * am + (u & 3) + 64 * (u >> 2);                     \
      const int gq = qb * 128 + row;                                        \
      const int sw = ((row & 7) ^ ((row >> 2) & 7)) << 2;                   \
      uint32_t k0 = fkey(fmaf(-2.f, acc[u][(BASE) + 0], sc[(BASE) + 0]));   \
      uint32_t k1 = fkey(fmaf(-2.f, acc[u][(BASE) + 1], sc[(BASE) + 1]));   \
      uint32_t k2 = fkey(fmaf(-2.f, acc[u][(BASE) + 2], sc[(BASE) + 2]));   \
      uint32_t k3 = fkey(fmaf(-2.f, acc[u][(BASE) + 3], sc[(BASE) + 3]));   \
      if (jbase + 0 == gq) k0 = 0xFFFFFFFFu;                                \
      if (jbase + 1 == gq) k1 = 0xFFFFFFFFu;                                \
      if (jbase + 2 == gq) k2 = 0xFFFFFFFFu;                                \
      if (jbase + 3 == gq) k3 = 0xFFFFFFFFu;                                \
      *(uint4*)&S[row * 32 + (cc ^ sw)] = make_uint4(k0, k1, k2, k3);       \
    }                                                                       \
  }

#define COMMIT_CS()                                                         \
  {                                                                         \
    Cs[(ck + 0) * 128 + cn] = p0.x;  Cs[(ck + 1) * 128 + cn] = p0.y;        \
    Cs[(ck + 2) * 128 + cn] = p0.z;  Cs[(ck + 3) * 128 + cn] = p0.w;        \
    Cs[(ck + 4) * 128 + cn] = p1.x;  Cs[(ck + 5) * 128 + cn] = p1.y;        \
    Cs[(ck + 6) * 128 + cn] = p1.z;  Cs[(ck + 7) * 128 + cn] = p1.w;        \
    Cs[(ck + 8) * 128 + cn] = p2.x;  Cs[(ck + 9) * 128 + cn] = p2.y;        \
    Cs[(ck + 10) * 128 + cn] = p2.z; Cs[(ck + 11) * 128 + cn] = p2.w;       \
    Cs[(ck + 12) * 128 + cn] = p3.x; Cs[(ck + 13) * 128 + cn] = p3.y;       \
    Cs[(ck + 14) * 128 + cn] = p3.z; Cs[(ck + 15) * 128 + cn] = p3.w;       \
  }

#define ISSUE_CS(BASEROW, KOFF)                                             \
  {                                                                         \
    const float* src_ = &x[(size_t)((BASEROW) + cn) * LDX + (KOFF) + ck];   \
    p0 = *(const float4*)&src_[0];                                          \
    p1 = *(const float4*)&src_[4];                                          \
    p2 = *(const float4*)&src_[8];                                          \
    p3 = *(const float4*)&src_[12];                                         \
  }

template <int LDX>
__global__ __launch_bounds__(256, 2) void knn_gemm_kernel(
    const float* __restrict__ x, const float* __restrict__ sq,
    uint32_t* __restrict__ pk) {
  __shared__ float Qs[64 * 128];      // [k][q]
  __shared__ uint32_t CsS[32 * 128];  // Cs floats during compute; S keys
  float* const Cs = (float*)CsS;
  uint32_t* const S = CsS;
  const int t = threadIdx.x;
  const int qb = blockIdx.x;  // 0..63
  const int ch = blockIdx.y;  // 0..7 (subset cands ch*256 .. +255)
  const int am = t & 15;
  const int bg = (t >> 4) & 15;
  const int cn = t & 127;
  const int ck = (t >> 7) * 16;

  {  // Q stage
    const int q = t & 127;
    const int k0 = (t >> 7) * 32;
    const float* src = &x[(size_t)(qb * 128 + q) * LDX + k0];
#pragma unroll
    for (int c = 0; c < 8; ++c) {
      float4 v = *(const float4*)&src[c * 4];
      Qs[(k0 + c * 4 + 0) * 128 + q] = v.x;
      Qs[(k0 + c * 4 + 1) * 128 + q] = v.y;
      Qs[(k0 + c * 4 + 2) * 128 + q] = v.z;
      Qs[(k0 + c * 4 + 3) * 128 + q] = v.w;
    }
  }

  const int selq = t & 127, part = t >> 7;
  uint32_t dreg[KSEL];
#pragma unroll
  for (int r = 0; r < KSEL; ++r) dreg[r] = 0xFFFFFFFFu;

  float4 p0, p1, p2, p3;
  ISSUE_CS(ch * 256, 0)

#pragma unroll 1
  for (int tile = 0; tile < 2; ++tile) {
    const int cb = ch * 256 + tile * 128;
    float acc[8][8] = {};
#pragma unroll
    for (int kh = 0; kh < 2; ++kh) {
      __syncthreads();
      COMMIT_CS()
      if (kh == 0) {
        ISSUE_CS(cb, 32)
      } else if (tile == 0) {
        ISSUE_CS(cb + 128, 0)
      }
      __syncthreads();
#pragma unroll 4
      for (int k2 = 0; k2 < 32; ++k2) {
        const int k = kh * 32 + k2;
        float4 A0 = *(const float4*)&Qs[k * 128 + 4 * am];
        float4 A1 = *(const float4*)&Qs[k * 128 + 4 * am + 64];
        float4 B0 = *(const float4*)&Cs[k2 * 128 + 4 * bg];
        float4 B1 = *(const float4*)&Cs[k2 * 128 + 4 * bg + 64];
        float a[8] = {A0.x, A0.y, A0.z, A0.w, A1.x, A1.y, A1.z, A1.w};
        float b[8] = {B0.x, B0.y, B0.z, B0.w, B1.x, B1.y, B1.z, B1.w};
#pragma unroll
        for (int u = 0; u < 8; ++u)
#pragma unroll
          for (int v = 0; v < 8; ++v) acc[u][v] = fmaf(a[u], b[v], acc[u][v]);
      }
    }
    float4 s0 = *(const float4*)&sq[cb + 4 * bg];
    float4 s1 = *(const float4*)&sq[cb + 4 * bg + 64];
    float sc[8] = {s0.x, s0.y, s0.z, s0.w, s1.x, s1.y, s1.z, s1.w};

    const int qlow = bg >> 3;
    for (int qr = 0; qr < 4; ++qr) {
      __syncthreads();
      if (qr == qlow) WRITE_S(qr, 0);
      if (qr == 2 + qlow) WRITE_S(qr, 4);
      __syncthreads();
      const int swr = ((selq & 7) ^ ((selq >> 2) & 7)) << 2;
#pragma unroll
      for (int g_ = 0; g_ < 4; ++g_) {
        const int cc = part * 16 + g_ * 4;
        uint4 sv = *(const uint4*)&S[selq * 32 + (cc ^ swr)];
        uint32_t kv[4] = {sv.x, sv.y, sv.z, sv.w};
#pragma unroll
        for (int e = 0; e < 4; ++e) {
          if (kv[e] < dreg[KSEL - 1]) insert8k(dreg, kv[e]);
        }
      }
    }
  }
  const int l = ch * 2 + part;  // 16 lists
  uint32_t* pkq = pk + ((size_t)l * NPTS + (qb * 128 + selq)) * KSEL;
#pragma unroll
  for (int r = 0; r < KSEL; ++r) pkq[r] = dreg[r];
}

// ---------------------------------------------------------------------------
// Tournament over 16 sorted 8-entry key-lists -> Tf[q] = 20th distance of
// the union + mscale*sqrt(sq_q * max_j sq_j). mscale=0 for the exact d3
// path; 1e-4 for the split-bf16 filter (error bound 2^-17, 13x headroom).
// ---------------------------------------------------------------------------
__global__ __launch_bounds__(256) void knn_mergeT_kernel(
    const uint32_t* __restrict__ pk, const float* __restrict__ sq,
    const float* __restrict__ nmax2, float* __restrict__ Tf, float mscale) {
  __shared__ uint32_t sk[16][16][KSEL];
  const int t = threadIdx.x;
  const int ql = t >> 4;
  const int l = t & 15;
  const int q = blockIdx.x * 16 + ql;
  const uint32_t* pkq = pk + ((size_t)l * NPTS + q) * KSEL;
#pragma unroll
  for (int r = 0; r < KSEL; ++r) sk[ql][l][r] = pkq[r];
  __syncthreads();
  int ptr = 0;
  uint32_t k = 0;
#pragma unroll 1
  for (int s = 0; s < KNN; ++s) {
    k = (ptr < KSEL) ? sk[ql][l][ptr] : 0xFFFFFFFFu;
    int src = l;
#pragma unroll
    for (int off = 8; off >= 1; off >>= 1) {
      uint32_t ok = __shfl_xor(k, off, 16);
      int osrc = __shfl_xor(src, off, 16);
      bool take = (ok < k) || (ok == k && osrc < src);
      k = take ? ok : k;
      src = take ? osrc : src;
    }
    if (l == src) ptr++;
  }
  if (l == 0) Tf[q] = unkey(k) + mscale * sqrtf(sq[q] * nmax2[0]);
}

// ---------------------------------------------------------------------------
// 64-D MFMA recover, split-bf16. ROUND-22: multi-c-tile blocks. Rounds
// 17-21 proved dur (~104us) invariant to occupancy, tile shape, and
// fragment source -- the untested axis is work-per-block (4096-8192 tiny
// blocks paying fixed costs for ~200cy of MFMA each). Now grid (64,16) =
// 1024 blocks; each block stages its A-tile ONCE (36.9 KB LDS) and loops
// over 8 candidate tiles (B single-buffered in LDS with register prefetch
// across iterations), survivors accumulate in one LDS list flushed once.
// Fragment values bit-identical.
// ---------------------------------------------------------------------------
__global__ __launch_bounds__(256, 2) void knn_recover_mfma_kernel(
    const ushort* __restrict__ xh, const ushort* __restrict__ xl,
    const float* __restrict__ sq, const float* __restrict__ Tf,
    uint32_t* __restrict__ cnt, int* __restrict__ cj) {
  __shared__ ushort Ah_s[128 * 72];  // 18.4 KB, row stride 144B
  __shared__ ushort Al_s[128 * 72];  // 18.4 KB
  __shared__ ushort Bh_s[64 * 72];   // 9.2 KB
  __shared__ ushort Bl_s[64 * 72];   // 9.2 KB
  __shared__ uint32_t nsurv;
  __shared__ uint2 surv[LCAPR];      // 8 KB
  const int t = threadIdx.x;
  const int w = t >> 6, l = t & 63;
  const int qbase = blockIdx.x * 128;
  const int cgrp = blockIdx.y * 512;  // 8 c-tiles of 64
  const int q0 = qbase + w * 32;      // wave's 32 query rows
  const int lr = l & 31;
  const int ko = (l >> 5) * 8;
  const int rowbase = (l >> 5) * 4;

  // B staging geometry: thread covers 64B of one plane
  const int bpl = t >> 7;             // 0: h-plane, 1: l-plane
  const int brr = (t & 127) >> 1;     // B row 0..63
  const int bhalf = t & 1;            // 64B half

  if (t == 0) nsurv = 0;

  {  // stage A: 128 rows x 128B x 2 planes, fully coalesced (once per block)
    const int row = t >> 1, half = t & 1;
    const uint4* sh = (const uint4*)&xh[(size_t)(qbase + row) * 64 + half * 32];
    const uint4* sl = (const uint4*)&xl[(size_t)(qbase + row) * 64 + half * 32];
    uint4* dh = (uint4*)&Ah_s[row * 72 + half * 32];
    uint4* dl = (uint4*)&Al_s[row * 72 + half * 32];
#pragma unroll
    for (int i = 0; i < 4; ++i) { dh[i] = sh[i]; dl[i] = sl[i]; }
  }

  // preload thresholds for the 16 output rows this lane touches
  float tq[16];
#pragma unroll
  for (int r = 0; r < 16; ++r)
    tq[r] = Tf[q0 + (r & 3) + 8 * (r >> 2) + rowbase];

  // issue B regs for it = 0
  uint4 pb[4];
  {
    const ushort* src = bpl ? xl : xh;
    const uint4* s = (const uint4*)&src[(size_t)(cgrp + brr) * 64 + bhalf * 32];
#pragma unroll
    for (int i = 0; i < 4; ++i) pb[i] = s[i];
  }
  __syncthreads();  // A staged + nsurv visible

#pragma unroll 1
  for (int it = 0; it < 8; ++it) {
    const int cbase = cgrp + it * 64;
    {  // commit B
      ushort* dst = bpl ? Bl_s : Bh_s;
      uint4* d = (uint4*)&dst[brr * 72 + bhalf * 32];
#pragma unroll
      for (int i = 0; i < 4; ++i) d[i] = pb[i];
    }
    if (it < 7) {  // issue next B (hides under MFMA below)
      const ushort* src = bpl ? xl : xh;
      const uint4* s =
          (const uint4*)&src[(size_t)(cbase + 64 + brr) * 64 + bhalf * 32];
#pragma unroll
      for (int i = 0; i < 4; ++i) pb[i] = s[i];
    }
    __syncthreads();  // B visible

    f32x16 acc[2] = {};
#pragma unroll
    for (int kk = 0; kk < 4; ++kk) {
      const int cu = kk * 16 + ko;  // ushort column
      bf16x8 Ah, Al, Bh[2], Bl[2];
      {
        const int row = w * 32 + lr;
        Ah = *(const bf16x8*)&Ah_s[row * 72 + cu];
        Al = *(const bf16x8*)&Al_s[row * 72 + cu];
      }
#pragma unroll
      for (int ct = 0; ct < 2; ++ct) {
        const int row = ct * 32 + lr;
        Bh[ct] = *(const bf16x8*)&Bh_s[row * 72 + cu];
        Bl[ct] = *(const bf16x8*)&Bl_s[row * 72 + cu];
      }
#pragma unroll
      for (int ct = 0; ct < 2; ++ct) {
        acc[ct] = __builtin_amdgcn_mfma_f32_32x32x16_bf16(Ah, Bh[ct], acc[ct],
                                                          0, 0, 0);
        acc[ct] = __builtin_amdgcn_mfma_f32_32x32x16_bf16(Ah, Bl[ct], acc[ct],
                                                          0, 0, 0);
        acc[ct] = __builtin_amdgcn_mfma_f32_32x32x16_bf16(Al, Bh[ct], acc[ct],
                                                          0, 0, 0);
      }
    }

#pragma unroll
    for (int ct = 0; ct < 2; ++ct) {
      const int j = cbase + ct * 32 + lr;
      const float sqj = sq[j];
#pragma unroll
      for (int r = 0; r < 16; ++r) {
        const int gq = q0 + (r & 3) + 8 * (r >> 2) + rowbase;
        float d = fmaf(-2.f, acc[ct][r], sqj);
        if (j != gq && d <= tq[r]) {
          uint32_t idx = atomicAdd(&nsurv, 1u);  // LDS atomic
          if (idx < (uint32_t)LCAPR) {
            surv[idx] = make_uint2((uint32_t)gq, (uint32_t)j);
          } else {  // overflow fallback: direct append (correctness kept)
            uint32_t slot = atomicAdd(&cnt[gq], 1u);
            if (slot < (uint32_t)CAP64) cj[(size_t)gq * CAP64 + slot] = j;
          }
        }
      }
    }
    __syncthreads();  // epilogue reads of B done -> safe to overwrite
  }

  const uint32_t nv = min(nsurv, (uint32_t)LCAPR);
#pragma unroll 1
  for (uint32_t i = t; i < nv; i += 256) {
    uint2 e = surv[i];
    uint32_t slot = atomicAdd(&cnt[e.x], 1u);
    if (slot < (uint32_t)CAP64) cj[(size_t)e.x * CAP64 + slot] = (int)e.y;
  }
}

// ---------------------------------------------------------------------------
// 64-D final: exact fp32 re-rank of <=CAP64 survivors. One wave per query.
// ---------------------------------------------------------------------------
template <int LDX>
__global__ __launch_bounds__(256) void knn_final64_kernel(
    const float* __restrict__ x, const float* __restrict__ sq,
    const uint32_t* __restrict__ cnt, const int* __restrict__ cj,
    int* __restrict__ idx_out) {
  __shared__ float xqs[4][64];
  const int t = threadIdx.x, w = t >> 6, l = t & 63;
  const int q = blockIdx.x * 4 + w;
  if (l < 16)
    *(float4*)&xqs[w][l * 4] = *(const float4*)&x[(size_t)q * LDX + l * 4];
  __syncthreads();
  const int n = (int)min(cnt[q], (uint32_t)CAP64);
  uint32_t ks[8]; int js[8];
#pragma unroll
  for (int r = 0; r < 8; ++r) { ks[r] = 0xFFFFFFFFu; js[r] = 0x7fffffff; }
#pragma unroll 1
  for (int it = 0; it < 8; ++it) {
    const int c = l + it * 64;
    if (c < n) {
      const int j = cj[(size_t)q * CAP64 + c];
      const float* xj = &x[(size_t)j * LDX];
      float dot = 0.f;
#pragma unroll
      for (int e = 0; e < 16; ++e) {
        float4 a = *(const float4*)&xj[e * 4];
        float4 b = *(const float4*)&xqs[w][e * 4];
        dot = fmaf(a.x, b.x, dot);
        dot = fmaf(a.y, b.y, dot);
        dot = fmaf(a.z, b.z, dot);
        dot = fmaf(a.w, b.w, dot);
      }
      float d = fmaf(-2.f, dot, sq[j]);
      uint32_t ck = fkey(d);
      int ci = j;
#pragma unroll
      for (int r = 0; r < 8; ++r) {  // tie-aware sorted insert
        bool sw = (ck < ks[r]) || (ck == ks[r] && ci < js[r]);
        uint32_t ok = ks[r]; int oj = js[r];
        ks[r] = sw ? ck : ok; js[r] = sw ? ci : oj;
        ck = sw ? ok : ck; ci = sw ? oj : ci;
      }
    }
  }
#pragma unroll 1
  for (int s = 0; s < KNN; ++s) {
    uint32_t mk = ks[0];
    int mj = js[0];
#pragma unroll
    for (int off = 32; off >= 1; off >>= 1) {
      uint32_t ok = __shfl_xor(mk, off, 64);
      int oj = __shfl_xor(mj, off, 64);
      bool take = (ok < mk) || (ok == mk && oj < mj);
      mk = take ? ok : mk;
      mj = take ? oj : mj;
    }
    if (ks[0] == mk && js[0] == mj) {  // j unique per query -> unique winner
#pragma unroll
      for (int r = 0; r < 7; ++r) { ks[r] = ks[r + 1]; js[r] = js[r + 1]; }
      ks[7] = 0xFFFFFFFFu; js[7] = 0x7fffffff;
    }
    if (l == 0) idx_out[(size_t)q * KNN + s] = mj;
  }
}

// ---------------------------------------------------------------------------
// 3-D approx pass: key-only top-8 over QUARTER subset (cands 0..2047).
// ---------------------------------------------------------------------------
__global__ __launch_bounds__(256) void knn_d3k_kernel(
    const float* __restrict__ x, const float* __restrict__ sq,
    uint32_t* __restrict__ pk) {
  __shared__ float4 Ct[128];
  const int t = threadIdx.x;
  const int q = blockIdx.x * 256 + t;
  const int ch = blockIdx.y;  // 0..15
  const int cb = ch * 128;
  if (t < 128)
    Ct[t] = make_float4(x[(cb + t) * 3], x[(cb + t) * 3 + 1],
                        x[(cb + t) * 3 + 2], sq[cb + t]);
  const float xi0 = x[q * 3], xi1 = x[q * 3 + 1], xi2 = x[q * 3 + 2];
  uint32_t dreg[KSEL];
#pragma unroll
  for (int r = 0; r < KSEL; ++r) dreg[r] = 0xFFFFFFFFu;
  __syncthreads();
#pragma unroll 1
  for (int c = 0; c < 128; ++c) {
    float4 cv = Ct[c];
    int j = cb + c;
    float val = fmaf(-2.f, xi0 * cv.x + xi1 * cv.y + xi2 * cv.z, cv.w);
    uint32_t key = fkey(val);
    if (j != q && key < dreg[KSEL - 1]) insert8k(dreg, key);
  }
  uint32_t* pkq = pk + ((size_t)ch * NPTS + q) * KSEL;
#pragma unroll
  for (int r = 0; r < KSEL; ++r) pkq[r] = dreg[r];
}

// ---------------------------------------------------------------------------
// 3-D recovery: stream all 8192 candidates, compact d <= Tf.
// Two-level LDS survivor append (round 17).
// ---------------------------------------------------------------------------
__global__ __launch_bounds__(256) void knn_d3_recover_kernel(
    const float* __restrict__ x, const float* __restrict__ sq,
    const float* __restrict__ Tf, uint32_t* __restrict__ cnt,
    uint32_t* __restrict__ cd, int* __restrict__ cj) {
  __shared__ float4 Ct[256];
  __shared__ uint32_t nsurv;
  __shared__ uint2 surv[LCAP];  // 16 KB
  const int t = threadIdx.x;
  const int q0 = blockIdx.x * 256;
  const int q = q0 + t;
  const int cb = blockIdx.y * 256;
  if (t == 0) nsurv = 0;
  Ct[t] = make_float4(x[(cb + t) * 3], x[(cb + t) * 3 + 1],
                      x[(cb + t) * 3 + 2], sq[cb + t]);
  const float xi0 = x[q * 3], xi1 = x[q * 3 + 1], xi2 = x[q * 3 + 2];
  const float Tq = Tf[q];
  __syncthreads();  // covers Ct + nsurv
#pragma unroll 1
  for (int c = 0; c < 256; ++c) {
    float4 cv = Ct[c];
    int j = cb + c;
    float val = fmaf(-2.f, xi0 * cv.x + xi1 * cv.y + xi2 * cv.z, cv.w);
    if (j != q && val <= Tq) {
      uint32_t idx = atomicAdd(&nsurv, 1u);  // LDS atomic
      if (idx < (uint32_t)LCAP) {
        surv[idx] = make_uint2(fkey(val), ((uint32_t)t << 16) | (uint32_t)j);
      } else {  // overflow fallback
        uint32_t slot = atomicAdd(&cnt[q], 1u);
        if (slot < (uint32_t)CAPD3) {
          cd[(size_t)q * CAPD3 + slot] = fkey(val);
          cj[(size_t)q * CAPD3 + slot] = j;
        }
      }
    }
  }
  __syncthreads();
  const uint32_t nv = min(nsurv, (uint32_t)LCAP);
#pragma unroll 1
  for (uint32_t i = t; i < nv; i += 256) {
    uint2 e = surv[i];
    const int qq = q0 + (int)(e.y >> 16);
    const int jj = (int)(e.y & 0xFFFFu);
    uint32_t slot = atomicAdd(&cnt[qq], 1u);
    if (slot < (uint32_t)CAPD3) {
      cd[(size_t)qq * CAPD3 + slot] = e.x;
      cj[(size_t)qq * CAPD3 + slot] = jj;
    }
  }
}

// ---------------------------------------------------------------------------
// d3 final select (exact keys in cd): one wave per query, 4/lane + tournament.
// ---------------------------------------------------------------------------
#define CSWAP(ka, ja, kb, jb)                                   \
  {                                                             \
    bool sw = (kb < ka) || (kb == ka && jb < ja);               \
    uint32_t tk = sw ? kb : ka; int tj = sw ? jb : ja;          \
    kb = sw ? ka : kb; jb = sw ? ja : jb;                       \
    ka = tk; ja = tj;                                           \
  }

__global__ __launch_bounds__(256) void knn_final_d3_kernel(
    const uint32_t* __restrict__ cnt, const uint32_t* __restrict__ cd,
    const int* __restrict__ cj, int* __restrict__ idx_out) {
  const int t = threadIdx.x;
  const int w = t >> 6;
  const int l = t & 63;
  const int q = blockIdx.x * 4 + w;
  const int n = (int)min(cnt[q], (uint32_t)CAPD3);
  uint32_t k0 = 0xFFFFFFFFu, k1 = 0xFFFFFFFFu, k2 = 0xFFFFFFFFu,
           k3 = 0xFFFFFFFFu;
  int j0 = 0x7fffffff, j1 = 0x7fffffff, j2 = 0x7fffffff, j3 = 0x7fffffff;
  if (l < n) { k0 = cd[(size_t)q * CAPD3 + l]; j0 = cj[(size_t)q * CAPD3 + l]; }
  if (l + 64 < n) { k1 = cd[(size_t)q * CAPD3 + l + 64]; j1 = cj[(size_t)q * CAPD3 + l + 64]; }
  if (l + 128 < n) { k2 = cd[(size_t)q * CAPD3 + l + 128]; j2 = cj[(size_t)q * CAPD3 + l + 128]; }
  if (l + 192 < n) { k3 = cd[(size_t)q * CAPD3 + l + 192]; j3 = cj[(size_t)q * CAPD3 + l + 192]; }
  CSWAP(k0, j0, k1, j1); CSWAP(k2, j2, k3, j3);
  CSWAP(k0, j0, k2, j2); CSWAP(k1, j1, k3, j3);
  CSWAP(k1, j1, k2, j2);
#pragma unroll 1
  for (int s = 0; s < KNN; ++s) {
    uint32_t mk = k0;
    int mj = j0;
#pragma unroll
    for (int off = 32; off >= 1; off >>= 1) {
      uint32_t ok = __shfl_xor(mk, off, 64);
      int oj = __shfl_xor(mj, off, 64);
      bool take = (ok < mk) || (ok == mk && oj < mj);
      mk = take ? ok : mk;
      mj = take ? oj : mj;
    }
    if (k0 == mk && j0 == mj) {
      k0 = k1; j0 = j1; k1 = k2; j1 = j2; k2 = k3; j2 = j3;
      k3 = 0xFFFFFFFFu; j3 = 0x7fffffff;
    }
    if (l == 0) idx_out[(size_t)q * KNN + s] = mj;
  }
}

// ---------------------------------------------------------------------------
// edge conv (unchanged)
// ---------------------------------------------------------------------------
__global__ __launch_bounds__(256) void edgeconv_kernel(
    const float* __restrict__ x, const int* __restrict__ idx,
    const float* __restrict__ W1, const float* __restrict__ b1,
    float* __restrict__ out) {
  const int i = blockIdx.x * 4 + (threadIdx.x >> 6);
  const int c = threadIdx.x & 63;
  float w0 = W1[c], w1 = W1[64 + c], w2 = W1[128 + c];
  float w3 = W1[192 + c], w4 = W1[256 + c], w5 = W1[320 + c];
  float xi0 = x[3 * i], xi1 = x[3 * i + 1], xi2 = x[3 * i + 2];
  float base = b1[c] + xi0 * w0 + xi1 * w1 + xi2 * w2;
  float m = -INFINITY;
#pragma unroll
  for (int k = 0; k < KNN; ++k) {
    int j = idx[i * KNN + k];
    float d0 = x[3 * j] - xi0, d1 = x[3 * j + 1] - xi1, d2 = x[3 * j + 2] - xi2;
    float h = base + d0 * w3 + d1 * w4 + d2 * w5;
    m = fmaxf(m, fmaxf(h, 0.f));
  }
  out[(size_t)i * 64 + c] = m;
}

// ---------------------------------------------------------------------------
// dilate (unchanged)
// ---------------------------------------------------------------------------
__global__ __launch_bounds__(256) void dilate_kernel(
    const float* __restrict__ xin, int ldin, const int* __restrict__ idx,
    const float* __restrict__ W, const float* __restrict__ bias,
    float* __restrict__ out, int ldout) {
  const int g = threadIdx.x >> 6;
  const int i = blockIdx.x * 4 + g;
  const int c = threadIdx.x & 63;
  __shared__ float dil[4][64];
  float m = -INFINITY;
#pragma unroll
  for (int k = 0; k < KNN; ++k) {
    int j = idx[i * KNN + k];
    m = fmaxf(m, xin[(size_t)j * ldin + c]);
  }
  dil[g][c] = m;
  __syncthreads();
  float acc = bias[c];
#pragma unroll
  for (int d = 0; d < 64; ++d) acc = fmaf(dil[g][d], W[d * 64 + c], acc);
  out[(size_t)i * ldout + c] = fmaxf(acc, 0.f) - xin[(size_t)i * ldin + c];
}

// ---------------------------------------------------------------------------
// BM=128 x BN tile fp32 GEMM with T14 register double-buffer (round 17).
// ---------------------------------------------------------------------------
template <int BN>
__global__ __launch_bounds__(256) void gemm128_kernel(
    const float* __restrict__ A, int K, int ldA, const float* __restrict__ W,
    int N, const float* __restrict__ bias, float* __restrict__ C, int ldC,
    int relu) {
  constexpr int VN = BN / 16;
  __shared__ float As[16 * 128];
  __shared__ float Bs[16 * BN];
  const int t = threadIdx.x;
  const int bn = blockIdx.x * BN;
  const int bm = blockIdx.y * 128;
  const int am = t & 15;
  const int bg = (t >> 4) & 15;
  const int m_ = t & 127;          // A staging row
  const int ka = (t >> 7) * 8;     // A staging k-base
  const int kb = t >> 4;           // B staging k-row
  const int nb = (t & 15) * (BN == 128 ? 8 : 4);  // B staging col
  float acc[8][VN] = {};
  float4 av0, av1, bv0, bv1;

  {  // issue k0 = 0
    const float* srcA = &A[(size_t)(bm + m_) * ldA + ka];
    av0 = *(const float4*)&srcA[0];
    av1 = *(const float4*)&srcA[4];
    const float* srcB = &W[(size_t)kb * N + bn + nb];
    bv0 = *(const float4*)&srcB[0];
    if constexpr (BN == 128) bv1 = *(const float4*)&srcB[4];
  }

  for (int k0 = 0; k0 < K; k0 += 16) {
    __syncthreads();  // prev compute done -> LDS reusable
    As[(ka + 0) * 128 + m_] = av0.x;
    As[(ka + 1) * 128 + m_] = av0.y;
    As[(ka + 2) * 128 + m_] = av0.z;
    As[(ka + 3) * 128 + m_] = av0.w;
    As[(ka + 4) * 128 + m_] = av1.x;
    As[(ka + 5) * 128 + m_] = av1.y;
    As[(ka + 6) * 128 + m_] = av1.z;
    As[(ka + 7) * 128 + m_] = av1.w;
    *(float4*)&Bs[kb * BN + nb] = bv0;
    if constexpr (BN == 128) *(float4*)&Bs[kb * BN + nb + 4] = bv1;
    if (k0 + 16 < K) {  // issue next K-step (hides under compute below)
      const float* srcA = &A[(size_t)(bm + m_) * ldA + k0 + 16 + ka];
      av0 = *(const float4*)&srcA[0];
      av1 = *(const float4*)&srcA[4];
      const float* srcB = &W[(size_t)(k0 + 16 + kb) * N + bn + nb];
      bv0 = *(const float4*)&srcB[0];
      if constexpr (BN == 128) bv1 = *(const float4*)&srcB[4];
    }
    __syncthreads();
#pragma unroll
    for (int k = 0; k < 16; ++k) {
      float4 A0 = *(const float4*)&As[k * 128 + 4 * am];
      float4 A1 = *(const float4*)&As[k * 128 + 4 * am + 64];
      float a[8] = {A0.x, A0.y, A0.z, A0.w, A1.x, A1.y, A1.z, A1.w};
      float b[VN];
      float4 B0 = *(const float4*)&Bs[k * BN + 4 * bg];
      b[0] = B0.x; b[1] = B0.y; b[2] = B0.z; b[3] = B0.w;
      if constexpr (BN == 128) {
        float4 B1 = *(const float4*)&Bs[k * BN + 4 * bg + 64];
        b[4] = B1.x; b[5] = B1.y; b[6] = B1.z; b[7] = B1.w;
      }
#pragma unroll
      for (int u = 0; u < 8; ++u)
#pragma unroll
        for (int v = 0; v < VN; ++v) acc[u][v] = fmaf(a[u], b[v], acc[u][v]);
    }
  }
#pragma unroll
  for (int u = 0; u < 8; ++u) {
    const int m = bm + 4 * am + (u & 3) + 64 * (u >> 2);
#pragma unroll
    for (int vq = 0; vq < VN / 4; ++vq) {
      const int n = bn + 4 * bg + 64 * vq;
      float4 o;
      float* po = (float*)&o;
#pragma unroll
      for (int e = 0; e < 4; ++e) {
        float val = acc[u][vq * 4 + e] + bias[n + e];
        po[e] = relu ? fmaxf(val, 0.f) : val;
      }
      *(float4*)&C[(size_t)m * ldC + n] = o;
    }
  }
}

// ---------------------------------------------------------------------------
// logits + log_softmax (unchanged)
// ---------------------------------------------------------------------------
__global__ __launch_bounds__(256) void final_kernel(
    const float* __restrict__ h3, const float* __restrict__ Wm3,
    const float* __restrict__ bm3, float* __restrict__ out) {
  __shared__ float hs[16][132];
  const int tid = threadIdx.x;
  const int r = tid >> 4, c = tid & 15;
  const int row0 = blockIdx.x * 16;
#pragma unroll
  for (int l = tid; l < 2048; l += 256)
    hs[l >> 7][l & 127] = h3[(size_t)row0 * 128 + l];
  __syncthreads();
  float acc = bm3[c];
#pragma unroll
  for (int d = 0; d < 128; ++d) acc = fmaf(hs[r][d], Wm3[d * 16 + c], acc);
  float mx = acc;
#pragma unroll
  for (int o = 8; o >= 1; o >>= 1) mx = fmaxf(mx, __shfl_xor(mx, o, 16));
  float e = expf(acc - mx);
  float s = e;
#pragma unroll
  for (int o = 8; o >= 1; o >>= 1) s += __shfl_xor(s, o, 16);
  out[(size_t)(row0 + r) * 16 + c] = (acc - mx) - logf(s);
}

// ---------------------------------------------------------------------------
extern "C" void kernel_launch(void* const* d_in, const int* in_sizes, int n_in,
                              void* d_out, int out_size, void* d_ws,
                              size_t ws_size, hipStream_t stream) {
  const float* x = (const float*)d_in[0];
  const float* W1 = (const float*)d_in[1];
  const float* b1 = (const float*)d_in[2];
  const float* Wd1 = (const float*)d_in[3];
  const float* bd1 = (const float*)d_in[4];
  const float* Wd2 = (const float*)d_in[5];
  const float* bd2 = (const float*)d_in[6];
  const float* Wd3 = (const float*)d_in[7];
  const float* bd3 = (const float*)d_in[8];
  const float* Wl = (const float*)d_in[9];
  const float* bl = (const float*)d_in[10];
  const float* Wm1 = (const float*)d_in[11];
  const float* bm1 = (const float*)d_in[12];
  const float* Wm2 = (const float*)d_in[13];
  const float* bm2 = (const float*)d_in[14];
  const float* Wm3 = (const float*)d_in[15];
  const float* bm3 = (const float*)d_in[16];
  float* out = (float*)d_out;

  char* ws = (char*)d_ws;
  float* sq = (float*)(ws + 0);              // 32 KB
  int* idxA = (int*)(ws + 32768);            // 640 KB
  float* xfeat = (float*)(ws + 1343488);     // 2 MB   [8192 x 64]
  float* xcat = (float*)(ws + 3440640);      // 6 MB   [8192 x 192]
  float* h1 = (float*)(ws + 9732096);        // 32 MB  [8192 x 1024]
  float* h2 = (float*)(ws + 43286528);       // 8 MB   [8192 x 256]
  float* h3 = (float*)(ws + 51675136);       // 4 MB   [8192 x 128]
  float* x1 = xcat;
  float* x2 = xcat + 64;
  float* x3 = xcat + 128;
  // knn scratch in the h1/h2 region (free until the head GEMMs):
  uint32_t* pk = (uint32_t*)(ws + 9732096);       // 4.19 MB -> 13926400
  uint32_t* cdD3 = (uint32_t*)(ws + 13926400);    // 8.39 MB -> 22315008
  int* cjD3 = (int*)(ws + 22315008);              // 8.39 MB -> 30703616
  float* Tf = (float*)(ws + 30703616);            // 32 KB   -> 30736384
  uint32_t* cnt = (uint32_t*)(ws + 30736384);     // 32 KB   -> 30769152
  unsigned int* nmax2u = (unsigned int*)(ws + 30769152);  // 64 B pad
  float* nmax2f = (float*)nmax2u;
  int* cj64 = (int*)(ws + 30769216);              // 16.78 MB -> 47546432
  ushort* xh = (ushort*)(ws + 47546432);          // 1 MB    -> 48595008
  ushort* xl = (ushort*)(ws + 48595008);          // 1 MB    -> 49643584

  // stage 1: edge conv on xyz (exact-key d3 path, margin 0)
  hipMemsetAsync(cnt, 0, 32768 + 64, stream);  // cnt + nmax2
  sqnorm_kernel<<<32, 256, 0, stream>>>(x, 3, 3, sq, nmax2u);
  knn_d3k_kernel<<<dim3(32, 16), 256, 0, stream>>>(x, sq, pk);
  knn_mergeT_kernel<<<NPTS / 16, 256, 0, stream>>>(pk, sq, nmax2f, Tf, 0.f);
  knn_d3_recover_kernel<<<dim3(32, 32), 256, 0, stream>>>(x, sq, Tf, cnt,
                                                          cdD3, cjD3);
  knn_final_d3_kernel<<<NPTS / 4, 256, 0, stream>>>(cnt, cdD3, cjD3, idxA);
  edgeconv_kernel<<<NPTS / 4, 256, 0, stream>>>(x, idxA, W1, b1, xfeat);

  // stage 2: three dilate blocks; 64-D kNN = fp32 quarter-subset threshold +
  // split-bf16 MFMA conservative filter (margin 1e-4) + exact fp32 re-rank
#define KNN64_PASS(XIN, LDX)                                                  \
  hipMemsetAsync(cnt, 0, 32768 + 64, stream);                                 \
  sqnorm_kernel<<<32, 256, 0, stream>>>(XIN, LDX, 64, sq, nmax2u);            \
  tobf16_kernel<<<256, 256, 0, stream>>>(XIN, LDX, xh, xl);                   \
  knn_gemm_kernel<LDX><<<dim3(64, 8), 256, 0, stream>>>(XIN, sq, pk);         \
  knn_mergeT_kernel<<<NPTS / 16, 256, 0, stream>>>(pk, sq, nmax2f, Tf,        \
                                                   1e-4f);                    \
  knn_recover_mfma_kernel<<<dim3(64, 16), 256, 0, stream>>>(xh, xl, sq, Tf,   \
                                                            cnt, cj64);       \
  knn_final64_kernel<LDX><<<NPTS / 4, 256, 0, stream>>>(XIN, sq, cnt, cj64,   \
                                                        idxA);

  KNN64_PASS(xfeat, 64)
  dilate_kernel<<<NPTS / 4, 256, 0, stream>>>(xfeat, 64, idxA, Wd1, bd1, x1,
                                              192);
  KNN64_PASS(x1, 192)
  dilate_kernel<<<NPTS / 4, 256, 0, stream>>>(x1, 192, idxA, Wd2, bd2, x2,
                                              192);
  KNN64_PASS(x2, 192)
  dilate_kernel<<<NPTS / 4, 256, 0, stream>>>(x2, 192, idxA, Wd3, bd3, x3,
                                              192);
#undef KNN64_PASS

  // stage 3: MLP head
  gemm128_kernel<128><<<dim3(1024 / 128, NPTS / 128), 256, 0, stream>>>(
      xcat, 192, 192, Wl, 1024, bl, h1, 1024, 1);
  gemm128_kernel<64><<<dim3(256 / 64, NPTS / 128), 256, 0, stream>>>(
      h1, 1024, 1024, Wm1, 256, bm1, h2, 256, 1);
  gemm128_kernel<64><<<dim3(128 / 64, NPTS / 128), 256, 0, stream>>>(
      h2, 256, 256, Wm2, 128, bm2, h3, 128, 1);
  final_kernel<<<NPTS / 16, 256, 0, stream>>>(h3, Wm3, bm3, out);
}